// Round 7
// baseline (2687.429 us; speedup 1.0000x reference)
//
#include <hip/hip_runtime.h>
#include <stdint.h>

#define S_LEN 512
#define BATCH 32
#define IDIM 512
#define HDIM 1024
#define NBLK 64
#define TAGB 0xC0DE0000u

typedef __attribute__((ext_vector_type(8))) short bf16x8;
typedef __attribute__((ext_vector_type(4))) float f32x4;
typedef __attribute__((ext_vector_type(4))) unsigned int u32x4;

typedef const __attribute__((address_space(1))) unsigned int as1_uint;
typedef __attribute__((address_space(3))) unsigned int as3_uint;

__device__ __forceinline__ unsigned short f2bf(float f) {
  unsigned int u = __float_as_uint(f);
  u = (u + 0x7fffu + ((u >> 16) & 1u)) >> 16;
  return (unsigned short)u;
}

__device__ __forceinline__ void gld_lds16(const void* g, void* l) {
  __builtin_amdgcn_global_load_lds((as1_uint*)g, (as3_uint*)l, 16, 0, 0);
}

__device__ __forceinline__ float sigm(float x) { return 1.f / (1.f + __expf(-x)); }
__device__ __forceinline__ float tanh_f(float x) { return 1.f - 2.f / (__expf(2.f * x) + 1.f); }

// tagged-exchange load: 16B = 2 x {bf16-pair, tag}
#define LDX4(dst, addr, OFF)                                             \
  asm volatile("global_load_dwordx4 %0, %1, off offset:" #OFF " sc0 sc1" \
               : "=v"(dst) : "v"(addr) : "memory")

// ---------------- cast x: f32 -> bf16, same layout ----------------
__global__ void k_cast_x(const float* __restrict__ src, unsigned short* __restrict__ dst, int n8) {
  int i0 = blockIdx.x * blockDim.x + threadIdx.x;
  int stride = gridDim.x * blockDim.x;
  for (int i = i0; i < n8; i += stride) {
    const float4* s4 = (const float4*)(src + (size_t)i * 8);
    float4 a = s4[0], b = s4[1];
    bf16x8 v;
    v[0] = (short)f2bf(a.x); v[1] = (short)f2bf(a.y); v[2] = (short)f2bf(a.z); v[3] = (short)f2bf(a.w);
    v[4] = (short)f2bf(b.x); v[5] = (short)f2bf(b.y); v[6] = (short)f2bf(b.z); v[7] = (short)f2bf(b.w);
    *(bf16x8*)(dst + (size_t)i * 8) = v;
  }
}

// ------- transpose-cast W: src [K][1024] f32 -> dst [1024][K] bf16 -------
__global__ void k_tcast_w(const float* __restrict__ src, unsigned short* __restrict__ dst, int K) {
  __shared__ float t[64][65];
  int k0 = blockIdx.x * 64, h0 = blockIdx.y * 64;
  int tid = threadIdx.x;
#pragma unroll 4
  for (int j = 0; j < 16; ++j) {
    int idx = j * 256 + tid;
    int kl = idx >> 6, hl = idx & 63;
    t[kl][hl] = src[(size_t)(k0 + kl) * HDIM + h0 + hl];
  }
  __syncthreads();
  int hl = tid >> 2, kg = tid & 3;
  unsigned short* drow = dst + (size_t)(h0 + hl) * K + k0 + kg * 16;
#pragma unroll
  for (int jj = 0; jj < 4; ++jj) {
    ushort4 v;
    v.x = f2bf(t[kg * 16 + jj * 4 + 0][hl]);
    v.y = f2bf(t[kg * 16 + jj * 4 + 1][hl]);
    v.z = f2bf(t[kg * 16 + jj * 4 + 2][hl]);
    v.w = f2bf(t[kg * 16 + jj * 4 + 3][hl]);
    *(ushort4*)(drow + jj * 4) = v;
  }
}

// ------------- input projection GEMM: (16384x512)@(512x4096) + bias -------------
__global__ __launch_bounds__(256) void k_proj(
    const unsigned short* __restrict__ xb, const unsigned short* __restrict__ wib,
    const float* __restrict__ b_i, const float* __restrict__ b_f,
    const float* __restrict__ b_g, const float* __restrict__ b_o,
    float* __restrict__ Xi, float* __restrict__ Xf, float* __restrict__ Xg,
    float* __restrict__ Xo) {
  __shared__ unsigned short As[128 * 64];
  __shared__ unsigned short Bs[128 * 64];
  int tid = threadIdx.x;
  int l = tid & 63, w = tid >> 6;
  int mt = blockIdx.x >> 5, nt = blockIdx.x & 31;
  int m0 = mt * 128, n0 = nt * 128;
  int g = nt >> 3;
  int wm = (w >> 1) * 64, wn = (w & 1) * 64;

  f32x4 acc[4][4];
  for (int mi = 0; mi < 4; ++mi)
    for (int ni = 0; ni < 4; ++ni)
      for (int r = 0; r < 4; ++r) acc[mi][ni][r] = 0.f;

  for (int kt = 0; kt < 8; ++kt) {
    int k0 = kt * 64;
#pragma unroll
    for (int j = 0; j < 4; ++j) {
      int idx = j * 256 + tid;
      int row = idx >> 3, c = idx & 7;
      int sc = c ^ (row & 7);
      gld_lds16(xb + (size_t)(m0 + row) * IDIM + k0 + sc * 8,
                (char*)As + ((j * 256 + (w << 6)) << 4));
      gld_lds16(wib + (size_t)(n0 + row) * IDIM + k0 + sc * 8,
                (char*)Bs + ((j * 256 + (w << 6)) << 4));
    }
    __syncthreads();
#pragma unroll
    for (int kst = 0; kst < 2; ++kst) {
      bf16x8 af[4], bfr[4];
#pragma unroll
      for (int mi = 0; mi < 4; ++mi) {
        int row = wm + mi * 16 + (l & 15);
        int c = (kst << 2) + (l >> 4);
        af[mi] = *(const bf16x8*)((const char*)As + row * 128 + ((c ^ (row & 7)) << 4));
      }
#pragma unroll
      for (int ni = 0; ni < 4; ++ni) {
        int row = wn + ni * 16 + (l & 15);
        int c = (kst << 2) + (l >> 4);
        bfr[ni] = *(const bf16x8*)((const char*)Bs + row * 128 + ((c ^ (row & 7)) << 4));
      }
#pragma unroll
      for (int mi = 0; mi < 4; ++mi)
#pragma unroll
        for (int ni = 0; ni < 4; ++ni)
          acc[mi][ni] = __builtin_amdgcn_mfma_f32_16x16x32_bf16(af[mi], bfr[ni], acc[mi][ni], 0, 0, 0);
    }
    __syncthreads();
  }

  const float* bias = g == 0 ? b_i : g == 1 ? b_f : g == 2 ? b_g : b_o;
  float* dst = g == 0 ? Xi : g == 1 ? Xf : g == 2 ? Xg : Xo;
#pragma unroll
  for (int ni = 0; ni < 4; ++ni) {
    int n = n0 + wn + ni * 16 + (l & 15);
    int h = n & 1023;
    float bv = bias[h];
#pragma unroll
    for (int mi = 0; mi < 4; ++mi)
#pragma unroll
      for (int r = 0; r < 4; ++r) {
        int m = m0 + wm + mi * 16 + ((l >> 4) << 2) + r;
        int b = m >> 9, s = m & 511;
        dst[(size_t)(s * BATCH + b) * HDIM + h] = acc[mi][ni][r] + bv;
      }
  }
}

// ---------------- persistent recurrence kernel ----------------
// 64 blocks x 256 threads, 2 independent sync domains (batch halves, M=16).
// Block = (dm=bid&1, hb=bid>>1): 32 h-dims, all 4 gates. Wave w = K-slice.
// h exchange: 2 rotating slots of self-validating 8B units {bf16-pair, tag}.
// Layout per slot/domain: unit (b, gp) at byte (b*512 + gp)*8, gp = h-pair idx.
// NO fences, NO flags, NO post-publish barrier: one LLC round trip per step.
__global__ __launch_bounds__(256, 1) void k_rnn(
    const unsigned short* __restrict__ whb, const float* __restrict__ h0,
    const float* __restrict__ c0, char* __restrict__ hx,
    const float* __restrict__ Xi, const float* __restrict__ Xf,
    const float* __restrict__ Xg, const float* __restrict__ Xo,
    float* __restrict__ csw, float* __restrict__ hseq, float* __restrict__ hT,
    float* __restrict__ cT) {
  __shared__ char lds[41472];  // [0,32K): partials [kw=4][nt=8]; [32K,+8.5K): act
  const int ACT = 32768;

  const int tid = threadIdx.x;
  const int w = tid >> 6, l = tid & 63;
  const int ln = l & 15, lk = l >> 4;
  const int bid = blockIdx.x;
  const int dm = bid & 1, hb = bid >> 1;

  float* isw = (float*)Xi; float* fsw = (float*)Xf;
  float* gsw = (float*)Xg; float* osw = (float*)Xo;
  const float* XW = (w == 0) ? Xi : (w == 1) ? Xf : (w == 2) ? Xg : Xo;

  // ---- W_h fragments: Breg[nt = g*2+hh][j], pinned into AGPRs ----
  bf16x8 Breg[8][8];
#pragma unroll
  for (int g = 0; g < 4; ++g)
#pragma unroll
    for (int hh = 0; hh < 2; ++hh)
#pragma unroll
      for (int j = 0; j < 8; ++j) {
        const size_t row = (size_t)((g << 10) + (hb << 5) + (hh << 4) + ln);
        Breg[g * 2 + hh][j] =
            *(const bf16x8*)(whb + (row << 10) + (w << 8) + (j << 5) + (lk << 3));
      }
#pragma unroll
  for (int nt = 0; nt < 8; ++nt)
#pragma unroll
    for (int j = 0; j < 8; ++j)
      asm volatile("" : "+a"(Breg[nt][j]));

  // ---- pointwise cell: thread owns (batch pb, h-pair hp) ----
  const int pb = tid >> 4, hp = tid & 15;
  const int bg = (dm << 4) + pb;          // global batch row
  const int gh = (hb << 5) + (hp << 1);   // global h dim
  const int o = hp << 1;
  // publish offset: domain + unit (b=pb, gp=hb*16+hp)
  char* const pub = hx + (dm << 16) + (pb << 12) + (((hb << 4) + hp) << 3);
  // consume base: domain + b=ln, gp-range start (w*128 + lk*4)
  const char* const cons = hx + (dm << 16) + (ln << 12) + (w << 10) + (lk << 5);

  float2 c = *(const float2*)&c0[((size_t)bg << 10) + gh];

  // ---- publish h0 (slot 0, tag TAGB+0) ----
  {
    float2 hv = *(const float2*)&h0[((size_t)bg << 10) + gh];
    unsigned long long pv =
        (unsigned long long)((unsigned int)f2bf(hv.x) | ((unsigned int)f2bf(hv.y) << 16)) |
        ((unsigned long long)TAGB << 32);
    __hip_atomic_store((unsigned long long*)pub, pv, __ATOMIC_RELAXED,
                       __HIP_MEMORY_SCOPE_AGENT);
  }

  for (int t = 0; t < S_LEN; ++t) {
    // ---- X[t] prefetch for this wave's gate (overlaps the poll) ----
    float xp[2][4];
    {
      const float* xb_ = XW + ((size_t)((t << 5) + (dm << 4)) << 10) + (hb << 5) + ln;
#pragma unroll
      for (int hh = 0; hh < 2; ++hh)
#pragma unroll
        for (int r = 0; r < 4; ++r)
          xp[hh][r] = xb_[((size_t)((lk << 2) + r) << 10) + (hh << 4)];
    }

    // ---- poll-load h_t: data IS the flag (tag-validated) ----
    const char* ab = cons + ((t & 1) << 17);
    const unsigned int want = TAGB + (unsigned int)t;
    u32x4 raw[16];
    while (true) {
      LDX4(raw[0], ab, 0);    LDX4(raw[1], ab, 16);
      LDX4(raw[2], ab, 128);  LDX4(raw[3], ab, 144);
      LDX4(raw[4], ab, 256);  LDX4(raw[5], ab, 272);
      LDX4(raw[6], ab, 384);  LDX4(raw[7], ab, 400);
      LDX4(raw[8], ab, 512);  LDX4(raw[9], ab, 528);
      LDX4(raw[10], ab, 640); LDX4(raw[11], ab, 656);
      LDX4(raw[12], ab, 768); LDX4(raw[13], ab, 784);
      LDX4(raw[14], ab, 896); LDX4(raw[15], ab, 912);
      asm volatile("s_waitcnt vmcnt(0)" ::: "memory");
      __builtin_amdgcn_sched_barrier(0);
      unsigned int ok = 1;
#pragma unroll
      for (int i = 0; i < 16; ++i)
        ok &= (unsigned int)(raw[i][1] == want) & (unsigned int)(raw[i][3] == want);
      if (__all((int)ok)) break;
    }

    // ---- assemble A-fragments (strip tags) ----
    bf16x8 a[8];
#pragma unroll
    for (int j = 0; j < 8; ++j) {
      u32x4 t4;
      t4[0] = raw[2 * j][0]; t4[1] = raw[2 * j][2];
      t4[2] = raw[2 * j + 1][0]; t4[3] = raw[2 * j + 1][2];
      a[j] = __builtin_bit_cast(bf16x8, t4);
    }

    // ---- partial GEMM over this wave's K-slice (64 MFMA) ----
    f32x4 acc[8];
#pragma unroll
    for (int nt = 0; nt < 8; ++nt)
#pragma unroll
      for (int r = 0; r < 4; ++r) acc[nt][r] = 0.f;
#pragma unroll
    for (int j = 0; j < 8; ++j)
#pragma unroll
      for (int nt = 0; nt < 8; ++nt)
        acc[nt] = __builtin_amdgcn_mfma_f32_16x16x32_bf16(a[j], Breg[nt][j], acc[nt], 0, 0, 0);

    // ---- write K-partials to LDS ----
#pragma unroll
    for (int nt = 0; nt < 8; ++nt)
      *(f32x4*)(lds + (((w << 3) + nt) << 10) + (l << 4)) = acc[nt];
    __syncthreads();

    // ---- gate-reduce: wave w sums gate w (nt=2w,2w+1) over 4 K-partials ----
#pragma unroll
    for (int hh = 0; hh < 2; ++hh) {
      const int nt = (w << 1) + hh;
      f32x4 s = *(const f32x4*)(lds + (nt << 10) + (l << 4));
#pragma unroll
      for (int kw = 1; kw < 4; ++kw) {
        f32x4 p = *(const f32x4*)(lds + (((kw << 3) + nt) << 10) + (l << 4));
#pragma unroll
        for (int r = 0; r < 4; ++r) s[r] += p[r];
      }
#pragma unroll
      for (int r = 0; r < 4; ++r) {
        float pre = s[r] + xp[hh][r];
        float act = (w == 2) ? tanh_f(pre) : sigm(pre);
        ((float*)(lds + ACT))[((w << 4) + (lk << 2) + r) * 34 + (hh << 4) + ln] = act;
      }
    }
    __syncthreads();

    // ---- pointwise ----
    const float* af = (const float*)(lds + ACT);
    float2 iv = *(const float2*)&af[(0 * 16 + pb) * 34 + o];
    float2 fv = *(const float2*)&af[(1 * 16 + pb) * 34 + o];
    float2 gv = *(const float2*)&af[(2 * 16 + pb) * 34 + o];
    float2 ov = *(const float2*)&af[(3 * 16 + pb) * 34 + o];

    c.x = fv.x * c.x + iv.x * gv.x;
    c.y = fv.y * c.y + iv.y * gv.y;
    float h0v = ov.x * tanh_f(c.x), h1v = ov.y * tanh_f(c.y);

    // ---- publish h_{t+1}: ONE tagged 8B store, fire-and-forget ----
    if (t < S_LEN - 1) {
      unsigned long long pv =
          (unsigned long long)((unsigned int)f2bf(h0v) | ((unsigned int)f2bf(h1v) << 16)) |
          ((unsigned long long)(TAGB + (unsigned int)(t + 1)) << 32);
      __hip_atomic_store((unsigned long long*)(pub + ((~t & 1) << 17)), pv,
                         __ATOMIC_RELAXED, __HIP_MEMORY_SCOPE_AGENT);
    }

    // ---- fire-and-forget outputs (drain during next poll) ----
    size_t oo = ((size_t)((t << 5) + bg) << 10) + gh;
    *(float2*)(isw + oo) = iv;
    *(float2*)(fsw + oo) = fv;
    *(float2*)(gsw + oo) = gv;
    *(float2*)(osw + oo) = ov;
    *(float2*)(csw + oo) = c;
    *(float2*)(hseq + (((size_t)(bg << 9) + t) << 10) + gh) = make_float2(h0v, h1v);
    if (t == S_LEN - 1) {
      *(float2*)(hT + ((size_t)bg << 10) + gh) = make_float2(h0v, h1v);
      *(float2*)(cT + ((size_t)bg << 10) + gh) = c;
    }
  }
}

extern "C" void kernel_launch(void* const* d_in, const int* in_sizes, int n_in,
                              void* d_out, int out_size, void* d_ws, size_t ws_size,
                              hipStream_t stream) {
  const float* x = (const float*)d_in[0];
  const float* h0 = (const float*)d_in[1];
  const float* c0 = (const float*)d_in[2];
  const float* Wi[4] = {(const float*)d_in[3], (const float*)d_in[6], (const float*)d_in[9], (const float*)d_in[12]};
  const float* Wh[4] = {(const float*)d_in[4], (const float*)d_in[7], (const float*)d_in[10], (const float*)d_in[13]};
  const float* bias[4] = {(const float*)d_in[5], (const float*)d_in[8], (const float*)d_in[11], (const float*)d_in[14]};

  float* out = (float*)d_out;
  float* R0 = out;               // hidden_seq (B,S,H)
  float* R1 = out + 16777216;    // hT
  float* R2 = R1 + 32768;        // cT
  float* R3 = R2 + 32768;        // fs (S,B,H)
  float* R4 = R3 + 16777216;     // is
  float* R5 = R4 + 16777216;     // os
  float* R6 = R5 + 16777216;     // gs
  float* R7 = R6 + 16777216;     // cs
  float* Xg_[4] = {R4, R3, R6, R5};  // stash region per gate i,f,g,o

  char* ws = (char*)d_ws;
  unsigned short* whb = (unsigned short*)ws;                // 8 MB
  unsigned short* wib = (unsigned short*)(ws + 8388608);    // 4 MB (dead after k_proj)
  char* hx = ws + 8388608;  // 256 KB tagged h-exchange, overlaps dead wib region

  unsigned short* xb = (unsigned short*)R0;  // x in bf16, stashed in hidden_seq region

  k_cast_x<<<2048, 256, 0, stream>>>(x, xb, (BATCH * S_LEN * IDIM) / 8);
  for (int g = 0; g < 4; ++g) {
    k_tcast_w<<<dim3(8, 16), 256, 0, stream>>>(Wi[g], wib + (size_t)g * 1024 * 512, 512);
    k_tcast_w<<<dim3(16, 16), 256, 0, stream>>>(Wh[g], whb + (size_t)g * 1024 * 1024, 1024);
  }
  k_proj<<<4096, 256, 0, stream>>>(xb, wib, bias[0], bias[1], bias[2], bias[3],
                                   Xg_[0], Xg_[1], Xg_[2], Xg_[3]);
  hipMemsetAsync(hx, 0, 262144, stream);  // clear stale tags (after k_proj: wib is dead)
  k_rnn<<<NBLK, 256, 0, stream>>>(whb, h0, c0, hx,
                                  Xg_[0], Xg_[1], Xg_[2], Xg_[3],
                                  R7, R0, R1, R2);
}

// Round 8
// 2371.729 us; speedup vs baseline: 1.1331x; 1.1331x over previous
//
#include <hip/hip_runtime.h>
#include <stdint.h>

#define S_LEN 512
#define BATCH 32
#define IDIM 512
#define HDIM 1024
#define NBLK 64

typedef __attribute__((ext_vector_type(8))) short bf16x8;
typedef __attribute__((ext_vector_type(4))) float f32x4;

typedef const __attribute__((address_space(1))) unsigned int as1_uint;
typedef __attribute__((address_space(3))) unsigned int as3_uint;

__device__ __forceinline__ unsigned short f2bf(float f) {
  unsigned int u = __float_as_uint(f);
  u = (u + 0x7fffu + ((u >> 16) & 1u)) >> 16;
  return (unsigned short)u;
}

__device__ __forceinline__ void gld_lds16(const void* g, void* l) {
  __builtin_amdgcn_global_load_lds((as1_uint*)g, (as3_uint*)l, 16, 0, 0);
}

__device__ __forceinline__ float sigm(float x) { return 1.f / (1.f + __expf(-x)); }
__device__ __forceinline__ float tanh_f(float x) { return 1.f - 2.f / (__expf(2.f * x) + 1.f); }

// ---------------- cast x: f32 -> bf16, same layout ----------------
__global__ void k_cast_x(const float* __restrict__ src, unsigned short* __restrict__ dst, int n8) {
  int i0 = blockIdx.x * blockDim.x + threadIdx.x;
  int stride = gridDim.x * blockDim.x;
  for (int i = i0; i < n8; i += stride) {
    const float4* s4 = (const float4*)(src + (size_t)i * 8);
    float4 a = s4[0], b = s4[1];
    bf16x8 v;
    v[0] = (short)f2bf(a.x); v[1] = (short)f2bf(a.y); v[2] = (short)f2bf(a.z); v[3] = (short)f2bf(a.w);
    v[4] = (short)f2bf(b.x); v[5] = (short)f2bf(b.y); v[6] = (short)f2bf(b.z); v[7] = (short)f2bf(b.w);
    *(bf16x8*)(dst + (size_t)i * 8) = v;
  }
}

// ------- transpose-cast W: src [K][1024] f32 -> dst [1024][K] bf16 -------
__global__ void k_tcast_w(const float* __restrict__ src, unsigned short* __restrict__ dst, int K) {
  __shared__ float t[64][65];
  int k0 = blockIdx.x * 64, h0 = blockIdx.y * 64;
  int tid = threadIdx.x;
#pragma unroll 4
  for (int j = 0; j < 16; ++j) {
    int idx = j * 256 + tid;
    int kl = idx >> 6, hl = idx & 63;
    t[kl][hl] = src[(size_t)(k0 + kl) * HDIM + h0 + hl];
  }
  __syncthreads();
  int hl = tid >> 2, kg = tid & 3;
  unsigned short* drow = dst + (size_t)(h0 + hl) * K + k0 + kg * 16;
#pragma unroll
  for (int jj = 0; jj < 4; ++jj) {
    ushort4 v;
    v.x = f2bf(t[kg * 16 + jj * 4 + 0][hl]);
    v.y = f2bf(t[kg * 16 + jj * 4 + 1][hl]);
    v.z = f2bf(t[kg * 16 + jj * 4 + 2][hl]);
    v.w = f2bf(t[kg * 16 + jj * 4 + 3][hl]);
    *(ushort4*)(drow + jj * 4) = v;
  }
}

// ------------- input projection GEMM: (16384x512)@(512x4096) + bias -------------
__global__ __launch_bounds__(256) void k_proj(
    const unsigned short* __restrict__ xb, const unsigned short* __restrict__ wib,
    const float* __restrict__ b_i, const float* __restrict__ b_f,
    const float* __restrict__ b_g, const float* __restrict__ b_o,
    float* __restrict__ Xi, float* __restrict__ Xf, float* __restrict__ Xg,
    float* __restrict__ Xo) {
  __shared__ unsigned short As[128 * 64];
  __shared__ unsigned short Bs[128 * 64];
  int tid = threadIdx.x;
  int l = tid & 63, w = tid >> 6;
  int mt = blockIdx.x >> 5, nt = blockIdx.x & 31;
  int m0 = mt * 128, n0 = nt * 128;
  int g = nt >> 3;
  int wm = (w >> 1) * 64, wn = (w & 1) * 64;

  f32x4 acc[4][4];
  for (int mi = 0; mi < 4; ++mi)
    for (int ni = 0; ni < 4; ++ni)
      for (int r = 0; r < 4; ++r) acc[mi][ni][r] = 0.f;

  for (int kt = 0; kt < 8; ++kt) {
    int k0 = kt * 64;
#pragma unroll
    for (int j = 0; j < 4; ++j) {
      int idx = j * 256 + tid;
      int row = idx >> 3, c = idx & 7;
      int sc = c ^ (row & 7);
      gld_lds16(xb + (size_t)(m0 + row) * IDIM + k0 + sc * 8,
                (char*)As + ((j * 256 + (w << 6)) << 4));
      gld_lds16(wib + (size_t)(n0 + row) * IDIM + k0 + sc * 8,
                (char*)Bs + ((j * 256 + (w << 6)) << 4));
    }
    __syncthreads();
#pragma unroll
    for (int kst = 0; kst < 2; ++kst) {
      bf16x8 af[4], bfr[4];
#pragma unroll
      for (int mi = 0; mi < 4; ++mi) {
        int row = wm + mi * 16 + (l & 15);
        int c = (kst << 2) + (l >> 4);
        af[mi] = *(const bf16x8*)((const char*)As + row * 128 + ((c ^ (row & 7)) << 4));
      }
#pragma unroll
      for (int ni = 0; ni < 4; ++ni) {
        int row = wn + ni * 16 + (l & 15);
        int c = (kst << 2) + (l >> 4);
        bfr[ni] = *(const bf16x8*)((const char*)Bs + row * 128 + ((c ^ (row & 7)) << 4));
      }
#pragma unroll
      for (int mi = 0; mi < 4; ++mi)
#pragma unroll
        for (int ni = 0; ni < 4; ++ni)
          acc[mi][ni] = __builtin_amdgcn_mfma_f32_16x16x32_bf16(af[mi], bfr[ni], acc[mi][ni], 0, 0, 0);
    }
    __syncthreads();
  }

  const float* bias = g == 0 ? b_i : g == 1 ? b_f : g == 2 ? b_g : b_o;
  float* dst = g == 0 ? Xi : g == 1 ? Xf : g == 2 ? Xg : Xo;
#pragma unroll
  for (int ni = 0; ni < 4; ++ni) {
    int n = n0 + wn + ni * 16 + (l & 15);
    int h = n & 1023;
    float bv = bias[h];
#pragma unroll
    for (int mi = 0; mi < 4; ++mi)
#pragma unroll
      for (int r = 0; r < 4; ++r) {
        int m = m0 + wm + mi * 16 + ((l >> 4) << 2) + r;
        int b = m >> 9, s = m & 511;
        dst[(size_t)(s * BATCH + b) * HDIM + h] = acc[mi][ni][r] + bv;
      }
  }
}

// ---------------- persistent recurrence kernel ----------------
// R5 protocol (counters + sc0sc1 frag loads) with critical-path trims:
// deferred output stores, empty-FIFO poll, per-wave flag increments.
__global__ __launch_bounds__(256, 1) void k_rnn(
    const unsigned short* __restrict__ whb, const float* __restrict__ h0,
    const float* __restrict__ c0, char* __restrict__ hbufA,
    char* __restrict__ hbufB, unsigned int* __restrict__ cnt,
    const float* __restrict__ Xi, const float* __restrict__ Xf,
    const float* __restrict__ Xg, const float* __restrict__ Xo,
    float* __restrict__ csw, float* __restrict__ hseq, float* __restrict__ hT,
    float* __restrict__ cT) {
  __shared__ char lds[41472];  // [0,32K): partials [kw=4][nt=8]; [32K,+8.5K): act
  const int ACT = 32768;

  const int tid = threadIdx.x;
  const int w = tid >> 6, l = tid & 63;
  const int ln = l & 15, lk = l >> 4;
  const int bid = blockIdx.x;
  const int dm = bid & 1, hb = bid >> 1;

  float* isw = (float*)Xi; float* fsw = (float*)Xf;
  float* gsw = (float*)Xg; float* osw = (float*)Xo;
  const float* XW = (w == 0) ? Xi : (w == 1) ? Xf : (w == 2) ? Xg : Xo;

  // ---- W_h fragments: Breg[nt = g*2+hh][j], pinned into AGPRs ----
  bf16x8 Breg[8][8];
#pragma unroll
  for (int g = 0; g < 4; ++g)
#pragma unroll
    for (int hh = 0; hh < 2; ++hh)
#pragma unroll
      for (int j = 0; j < 8; ++j) {
        const size_t row = (size_t)((g << 10) + (hb << 5) + (hh << 4) + ln);
        Breg[g * 2 + hh][j] =
            *(const bf16x8*)(whb + (row << 10) + (w << 8) + (j << 5) + (lk << 3));
      }
#pragma unroll
  for (int nt = 0; nt < 8; ++nt)
#pragma unroll
    for (int j = 0; j < 8; ++j)
      asm volatile("" : "+a"(Breg[nt][j]));

  // ---- pointwise cell: thread owns (batch pb, h-pair hp) ----
  const int pb = tid >> 4, hp = tid & 15;
  const int bg = (dm << 4) + pb;          // global batch row
  const int gh = (hb << 5) + (hp << 1);   // global h dim
  const int o = hp << 1;
  const int foff = (dm << 15) + (hb << 10) + ((o >> 3) << 8) + (pb << 4) + ((o & 7) << 1);
  unsigned int* const myflag = cnt + (((dm << 2) + (hb & 3)) << 5);

  float2 c = *(const float2*)&c0[((size_t)bg << 10) + gh];

  // deferred (previous-step) outputs held in registers
  float2 piv, pfv, pgv, pov, pc;
  float ph0 = 0.f, ph1 = 0.f;

  // ---- publish h0 stripe in fragment layout (per-wave flag) ----
  {
    float2 hv = *(const float2*)&h0[((size_t)bg << 10) + gh];
    unsigned int pv = (unsigned int)f2bf(hv.x) | ((unsigned int)f2bf(hv.y) << 16);
    __hip_atomic_store((unsigned int*)(hbufA + foff), pv, __ATOMIC_RELAXED,
                       __HIP_MEMORY_SCOPE_AGENT);
    asm volatile("s_waitcnt vmcnt(0)" ::: "memory");
    if (l == 0)
      __hip_atomic_fetch_add(myflag, 1u, __ATOMIC_RELAXED, __HIP_MEMORY_SCOPE_AGENT);
  }

  for (int t = 0; t < S_LEN; ++t) {
    const char* hin = (t & 1) ? hbufB : hbufA;
    char* hout = (t & 1) ? hbufA : hbufB;

    // ---- wait until this domain's 32 blocks (x4 waves) published h_t ----
    // FIFO is empty here: fastest possible detection for the straggler.
    {
      const unsigned int need = 32u * (unsigned int)(t + 1);
      const unsigned int* cp = cnt + (((dm << 2) + (l & 3)) << 5);
      while (true) {
        unsigned int v = __hip_atomic_load(cp, __ATOMIC_RELAXED, __HIP_MEMORY_SCOPE_AGENT);
        if (__all((l < 4) ? (int)(v >= need) : 1)) break;
        __builtin_amdgcn_s_sleep(1);
      }
    }
    __builtin_amdgcn_sched_barrier(0);

    // ---- A-fragments direct from LLC (bypass L1/L2) ----
    bf16x8 a[8];
    const char* abase = hin + (dm << 15);
#pragma unroll
    for (int j = 0; j < 8; ++j) {
      const char* ap = abase + (((w << 3) + j) << 10) + (l << 4);
      asm volatile("global_load_dwordx4 %0, %1, off sc0 sc1"
                   : "=v"(a[j]) : "v"(ap) : "memory");
    }
    asm volatile("s_waitcnt vmcnt(0)" ::: "memory");
    __builtin_amdgcn_sched_barrier(0);

    // ---- deferred stores of step t-1 outputs (drain during MFMA phase) ----
    if (t > 0) {
      size_t po = ((size_t)(((t - 1) << 5) + bg) << 10) + gh;
      *(float2*)(isw + po) = piv;
      *(float2*)(fsw + po) = pfv;
      *(float2*)(gsw + po) = pgv;
      *(float2*)(osw + po) = pov;
      *(float2*)(csw + po) = pc;
      *(float2*)(hseq + (((size_t)(bg << 9) + (t - 1)) << 10) + gh) = make_float2(ph0, ph1);
    }

    // ---- X[t] loads for this wave's gate (overlap MFMA) ----
    float xp[2][4];
    {
      const float* xb_ = XW + ((size_t)((t << 5) + (dm << 4)) << 10) + (hb << 5) + ln;
#pragma unroll
      for (int hh = 0; hh < 2; ++hh)
#pragma unroll
        for (int r = 0; r < 4; ++r)
          xp[hh][r] = xb_[((size_t)((lk << 2) + r) << 10) + (hh << 4)];
    }

    // ---- partial GEMM over this wave's K-slice (64 MFMA) ----
    f32x4 acc[8];
#pragma unroll
    for (int nt = 0; nt < 8; ++nt)
#pragma unroll
      for (int r = 0; r < 4; ++r) acc[nt][r] = 0.f;
#pragma unroll
    for (int j = 0; j < 8; ++j)
#pragma unroll
      for (int nt = 0; nt < 8; ++nt)
        acc[nt] = __builtin_amdgcn_mfma_f32_16x16x32_bf16(a[j], Breg[nt][j], acc[nt], 0, 0, 0);

    // ---- write K-partials to LDS ----
#pragma unroll
    for (int nt = 0; nt < 8; ++nt)
      *(f32x4*)(lds + (((w << 3) + nt) << 10) + (l << 4)) = acc[nt];
    __syncthreads();

    // ---- gate-reduce: wave w sums gate w (nt=2w,2w+1) over 4 K-partials ----
#pragma unroll
    for (int hh = 0; hh < 2; ++hh) {
      const int nt = (w << 1) + hh;
      f32x4 s = *(const f32x4*)(lds + (nt << 10) + (l << 4));
#pragma unroll
      for (int kw = 1; kw < 4; ++kw) {
        f32x4 p = *(const f32x4*)(lds + (((kw << 3) + nt) << 10) + (l << 4));
#pragma unroll
        for (int r = 0; r < 4; ++r) s[r] += p[r];
      }
#pragma unroll
      for (int r = 0; r < 4; ++r) {
        float pre = s[r] + xp[hh][r];
        float act = (w == 2) ? tanh_f(pre) : sigm(pre);
        ((float*)(lds + ACT))[((w << 4) + (lk << 2) + r) * 34 + (hh << 4) + ln] = act;
      }
    }
    __syncthreads();

    // ---- pointwise ----
    const float* af = (const float*)(lds + ACT);
    float2 iv = *(const float2*)&af[(0 * 16 + pb) * 34 + o];
    float2 fv = *(const float2*)&af[(1 * 16 + pb) * 34 + o];
    float2 gv = *(const float2*)&af[(2 * 16 + pb) * 34 + o];
    float2 ov = *(const float2*)&af[(3 * 16 + pb) * 34 + o];

    c.x = fv.x * c.x + iv.x * gv.x;
    c.y = fv.y * c.y + iv.y * gv.y;
    float h0v = ov.x * tanh_f(c.x), h1v = ov.y * tanh_f(c.y);

    // ---- publish h_{t+1}: store, per-wave ack, per-wave flag ----
    if (t < S_LEN - 1) {
      unsigned int pv = (unsigned int)f2bf(h0v) | ((unsigned int)f2bf(h1v) << 16);
      __hip_atomic_store((unsigned int*)(hout + foff), pv, __ATOMIC_RELAXED,
                         __HIP_MEMORY_SCOPE_AGENT);
      asm volatile("s_waitcnt vmcnt(0)" ::: "memory");
      if (l == 0)
        __hip_atomic_fetch_add(myflag, 1u, __ATOMIC_RELAXED, __HIP_MEMORY_SCOPE_AGENT);
    }

    // ---- stash outputs for deferred store next step ----
    piv = iv; pfv = fv; pgv = gv; pov = ov; pc = c; ph0 = h0v; ph1 = h1v;
  }

  // ---- final step's outputs ----
  {
    size_t po = ((size_t)(((S_LEN - 1) << 5) + bg) << 10) + gh;
    *(float2*)(isw + po) = piv;
    *(float2*)(fsw + po) = pfv;
    *(float2*)(gsw + po) = pgv;
    *(float2*)(osw + po) = pov;
    *(float2*)(csw + po) = pc;
    *(float2*)(hseq + (((size_t)(bg << 9) + (S_LEN - 1)) << 10) + gh) = make_float2(ph0, ph1);
    *(float2*)(hT + ((size_t)bg << 10) + gh) = make_float2(ph0, ph1);
    *(float2*)(cT + ((size_t)bg << 10) + gh) = pc;
  }
}

extern "C" void kernel_launch(void* const* d_in, const int* in_sizes, int n_in,
                              void* d_out, int out_size, void* d_ws, size_t ws_size,
                              hipStream_t stream) {
  const float* x = (const float*)d_in[0];
  const float* h0 = (const float*)d_in[1];
  const float* c0 = (const float*)d_in[2];
  const float* Wi[4] = {(const float*)d_in[3], (const float*)d_in[6], (const float*)d_in[9], (const float*)d_in[12]};
  const float* Wh[4] = {(const float*)d_in[4], (const float*)d_in[7], (const float*)d_in[10], (const float*)d_in[13]};
  const float* bias[4] = {(const float*)d_in[5], (const float*)d_in[8], (const float*)d_in[11], (const float*)d_in[14]};

  float* out = (float*)d_out;
  float* R0 = out;               // hidden_seq (B,S,H)
  float* R1 = out + 16777216;    // hT
  float* R2 = R1 + 32768;        // cT
  float* R3 = R2 + 32768;        // fs (S,B,H)
  float* R4 = R3 + 16777216;     // is
  float* R5 = R4 + 16777216;     // os
  float* R6 = R5 + 16777216;     // gs
  float* R7 = R6 + 16777216;     // cs
  float* Xg_[4] = {R4, R3, R6, R5};  // stash region per gate i,f,g,o

  char* ws = (char*)d_ws;
  unsigned short* whb = (unsigned short*)ws;                // 8 MB
  unsigned short* wib = (unsigned short*)(ws + 8388608);    // 4 MB
  char* hbufA = ws + 12582912;                              // 64 KB (2 domains x 32 KB)
  char* hbufB = ws + 12648448;                              // 64 KB
  unsigned int* cnt = (unsigned int*)(ws + 12713984);       // 8 x 128B counters

  unsigned short* xb = (unsigned short*)R0;  // x in bf16, stashed in hidden_seq region

  hipMemsetAsync(cnt, 0, 1024, stream);
  k_cast_x<<<2048, 256, 0, stream>>>(x, xb, (BATCH * S_LEN * IDIM) / 8);
  for (int g = 0; g < 4; ++g) {
    k_tcast_w<<<dim3(8, 16), 256, 0, stream>>>(Wi[g], wib + (size_t)g * 1024 * 512, 512);
    k_tcast_w<<<dim3(16, 16), 256, 0, stream>>>(Wh[g], whb + (size_t)g * 1024 * 1024, 1024);
  }
  k_proj<<<4096, 256, 0, stream>>>(xb, wib, bias[0], bias[1], bias[2], bias[3],
                                   Xg_[0], Xg_[1], Xg_[2], Xg_[3]);
  k_rnn<<<NBLK, 256, 0, stream>>>(whb, h0, c0, hbufA, hbufB, cnt,
                                  Xg_[0], Xg_[1], Xg_[2], Xg_[3],
                                  R7, R0, R1, R2);
}

// Round 9
// 1877.812 us; speedup vs baseline: 1.4311x; 1.2630x over previous
//
#include <hip/hip_runtime.h>
#include <stdint.h>

#define S_LEN 512
#define BATCH 32
#define IDIM 512
#define HDIM 1024
#define NBLK 64

typedef __attribute__((ext_vector_type(8))) short bf16x8;
typedef __attribute__((ext_vector_type(4))) float f32x4;

typedef const __attribute__((address_space(1))) unsigned int as1_uint;
typedef __attribute__((address_space(3))) unsigned int as3_uint;

__device__ __forceinline__ unsigned short f2bf(float f) {
  unsigned int u = __float_as_uint(f);
  u = (u + 0x7fffu + ((u >> 16) & 1u)) >> 16;
  return (unsigned short)u;
}

__device__ __forceinline__ void gld_lds16(const void* g, void* l) {
  __builtin_amdgcn_global_load_lds((as1_uint*)g, (as3_uint*)l, 16, 0, 0);
}

__device__ __forceinline__ float sigm(float x) { return 1.f / (1.f + __expf(-x)); }
__device__ __forceinline__ float tanh_f(float x) { return 1.f - 2.f / (__expf(2.f * x) + 1.f); }

// ---------------- cast x: f32 -> bf16, same layout ----------------
__global__ void k_cast_x(const float* __restrict__ src, unsigned short* __restrict__ dst, int n8) {
  int i0 = blockIdx.x * blockDim.x + threadIdx.x;
  int stride = gridDim.x * blockDim.x;
  for (int i = i0; i < n8; i += stride) {
    const float4* s4 = (const float4*)(src + (size_t)i * 8);
    float4 a = s4[0], b = s4[1];
    bf16x8 v;
    v[0] = (short)f2bf(a.x); v[1] = (short)f2bf(a.y); v[2] = (short)f2bf(a.z); v[3] = (short)f2bf(a.w);
    v[4] = (short)f2bf(b.x); v[5] = (short)f2bf(b.y); v[6] = (short)f2bf(b.z); v[7] = (short)f2bf(b.w);
    *(bf16x8*)(dst + (size_t)i * 8) = v;
  }
}

// ------- transpose-cast W: src [K][1024] f32 -> dst [1024][K] bf16 -------
__global__ void k_tcast_w(const float* __restrict__ src, unsigned short* __restrict__ dst, int K) {
  __shared__ float t[64][65];
  int k0 = blockIdx.x * 64, h0 = blockIdx.y * 64;
  int tid = threadIdx.x;
#pragma unroll 4
  for (int j = 0; j < 16; ++j) {
    int idx = j * 256 + tid;
    int kl = idx >> 6, hl = idx & 63;
    t[kl][hl] = src[(size_t)(k0 + kl) * HDIM + h0 + hl];
  }
  __syncthreads();
  int hl = tid >> 2, kg = tid & 3;
  unsigned short* drow = dst + (size_t)(h0 + hl) * K + k0 + kg * 16;
#pragma unroll
  for (int jj = 0; jj < 4; ++jj) {
    ushort4 v;
    v.x = f2bf(t[kg * 16 + jj * 4 + 0][hl]);
    v.y = f2bf(t[kg * 16 + jj * 4 + 1][hl]);
    v.z = f2bf(t[kg * 16 + jj * 4 + 2][hl]);
    v.w = f2bf(t[kg * 16 + jj * 4 + 3][hl]);
    *(ushort4*)(drow + jj * 4) = v;
  }
}

// ------------- input projection GEMM: (16384x512)@(512x4096) + bias -------------
__global__ __launch_bounds__(256) void k_proj(
    const unsigned short* __restrict__ xb, const unsigned short* __restrict__ wib,
    const float* __restrict__ b_i, const float* __restrict__ b_f,
    const float* __restrict__ b_g, const float* __restrict__ b_o,
    float* __restrict__ Xi, float* __restrict__ Xf, float* __restrict__ Xg,
    float* __restrict__ Xo) {
  __shared__ unsigned short As[128 * 64];
  __shared__ unsigned short Bs[128 * 64];
  int tid = threadIdx.x;
  int l = tid & 63, w = tid >> 6;
  int mt = blockIdx.x >> 5, nt = blockIdx.x & 31;
  int m0 = mt * 128, n0 = nt * 128;
  int g = nt >> 3;
  int wm = (w >> 1) * 64, wn = (w & 1) * 64;

  f32x4 acc[4][4];
  for (int mi = 0; mi < 4; ++mi)
    for (int ni = 0; ni < 4; ++ni)
      for (int r = 0; r < 4; ++r) acc[mi][ni][r] = 0.f;

  for (int kt = 0; kt < 8; ++kt) {
    int k0 = kt * 64;
#pragma unroll
    for (int j = 0; j < 4; ++j) {
      int idx = j * 256 + tid;
      int row = idx >> 3, c = idx & 7;
      int sc = c ^ (row & 7);
      gld_lds16(xb + (size_t)(m0 + row) * IDIM + k0 + sc * 8,
                (char*)As + ((j * 256 + (w << 6)) << 4));
      gld_lds16(wib + (size_t)(n0 + row) * IDIM + k0 + sc * 8,
                (char*)Bs + ((j * 256 + (w << 6)) << 4));
    }
    __syncthreads();
#pragma unroll
    for (int kst = 0; kst < 2; ++kst) {
      bf16x8 af[4], bfr[4];
#pragma unroll
      for (int mi = 0; mi < 4; ++mi) {
        int row = wm + mi * 16 + (l & 15);
        int c = (kst << 2) + (l >> 4);
        af[mi] = *(const bf16x8*)((const char*)As + row * 128 + ((c ^ (row & 7)) << 4));
      }
#pragma unroll
      for (int ni = 0; ni < 4; ++ni) {
        int row = wn + ni * 16 + (l & 15);
        int c = (kst << 2) + (l >> 4);
        bfr[ni] = *(const bf16x8*)((const char*)Bs + row * 128 + ((c ^ (row & 7)) << 4));
      }
#pragma unroll
      for (int mi = 0; mi < 4; ++mi)
#pragma unroll
        for (int ni = 0; ni < 4; ++ni)
          acc[mi][ni] = __builtin_amdgcn_mfma_f32_16x16x32_bf16(af[mi], bfr[ni], acc[mi][ni], 0, 0, 0);
    }
    __syncthreads();
  }

  const float* bias = g == 0 ? b_i : g == 1 ? b_f : g == 2 ? b_g : b_o;
  float* dst = g == 0 ? Xi : g == 1 ? Xf : g == 2 ? Xg : Xo;
#pragma unroll
  for (int ni = 0; ni < 4; ++ni) {
    int n = n0 + wn + ni * 16 + (l & 15);
    int h = n & 1023;
    float bv = bias[h];
#pragma unroll
    for (int mi = 0; mi < 4; ++mi)
#pragma unroll
      for (int r = 0; r < 4; ++r) {
        int m = m0 + wm + mi * 16 + ((l >> 4) << 2) + r;
        int b = m >> 9, s = m & 511;
        dst[(size_t)(s * BATCH + b) * HDIM + h] = acc[mi][ni][r] + bv;
      }
  }
}

// ---------------- persistent recurrence kernel ----------------
// R6 structure (2 domains x 32 blocks, W in AGPRs, frag-layout LLC exchange)
// with: (1) per-block SENTINEL stores (no atomic RMW), 8 sentinels/line so a
// wave's producer set is ONE line; (2) per-K-slice polling: wave w waits only
// for its 8 producer blocks; (3) counted-vmcnt staged A-load->MFMA pipeline.
__global__ __launch_bounds__(256, 1) void k_rnn(
    const unsigned short* __restrict__ whb, const float* __restrict__ h0,
    const float* __restrict__ c0, char* __restrict__ hbufA,
    char* __restrict__ hbufB, unsigned int* __restrict__ sent,
    const float* __restrict__ Xi, const float* __restrict__ Xf,
    const float* __restrict__ Xg, const float* __restrict__ Xo,
    float* __restrict__ csw, float* __restrict__ hseq, float* __restrict__ hT,
    float* __restrict__ cT) {
  __shared__ char lds[41472];  // [0,32K): partials [kw=4][nt=8]; [32K,+8.5K): act
  const int ACT = 32768;

  const int tid = threadIdx.x;
  const int w = tid >> 6, l = tid & 63;
  const int ln = l & 15, lk = l >> 4;
  const int bid = blockIdx.x;
  const int dm = bid & 1, hb = bid >> 1;

  float* isw = (float*)Xi; float* fsw = (float*)Xf;
  float* gsw = (float*)Xg; float* osw = (float*)Xo;
  const float* XW = (w == 0) ? Xi : (w == 1) ? Xf : (w == 2) ? Xg : Xo;

  // ---- W_h fragments: Breg[nt = g*2+hh][j], pinned into AGPRs ----
  bf16x8 Breg[8][8];
#pragma unroll
  for (int g = 0; g < 4; ++g)
#pragma unroll
    for (int hh = 0; hh < 2; ++hh)
#pragma unroll
      for (int j = 0; j < 8; ++j) {
        const size_t row = (size_t)((g << 10) + (hb << 5) + (hh << 4) + ln);
        Breg[g * 2 + hh][j] =
            *(const bf16x8*)(whb + (row << 10) + (w << 8) + (j << 5) + (lk << 3));
      }
#pragma unroll
  for (int nt = 0; nt < 8; ++nt)
#pragma unroll
    for (int j = 0; j < 8; ++j)
      asm volatile("" : "+a"(Breg[nt][j]));

  // ---- pointwise cell: thread owns (batch pb, h-pair hp) ----
  const int pb = tid >> 4, hp = tid & 15;
  const int bg = (dm << 4) + pb;          // global batch row
  const int gh = (hb << 5) + (hp << 1);   // global h dim
  const int o = hp << 1;
  const int foff = (dm << 15) + (hb << 10) + ((o >> 3) << 8) + (pb << 4) + ((o & 7) << 1);
  // sentinel slots: uint index = dm*128 + (hb>>3)*32 + (hb&7)*4  (16B stride, 8/line)
  unsigned int* const smy = sent + (dm << 7) + ((hb >> 3) << 5) + ((hb & 7) << 2);
  const unsigned int* const spoll = sent + (dm << 7) + (w << 5) + ((l & 7) << 2);

  float2 c = *(const float2*)&c0[((size_t)bg << 10) + gh];

  // ---- publish h0 stripe in fragment layout, sentinel tag=1 ----
  {
    float2 hv = *(const float2*)&h0[((size_t)bg << 10) + gh];
    unsigned int pv = (unsigned int)f2bf(hv.x) | ((unsigned int)f2bf(hv.y) << 16);
    __hip_atomic_store((unsigned int*)(hbufA + foff), pv, __ATOMIC_RELAXED,
                       __HIP_MEMORY_SCOPE_AGENT);
    asm volatile("s_waitcnt vmcnt(0)" ::: "memory");
    __syncthreads();
    if (tid == 0)
      __hip_atomic_store(smy, 1u, __ATOMIC_RELAXED, __HIP_MEMORY_SCOPE_AGENT);
  }

  for (int t = 0; t < S_LEN; ++t) {
    const char* hin = (t & 1) ? hbufB : hbufA;
    char* hout = (t & 1) ? hbufA : hbufB;

    // ---- X[t] loads, asm-pinned BEFORE the poll (drained by poll's vmcnt) ----
    float xp[2][4];
    {
      const float* xb_ = XW + ((size_t)((t << 5) + (dm << 4)) << 10) + (hb << 5) + ln;
#pragma unroll
      for (int hh = 0; hh < 2; ++hh)
#pragma unroll
        for (int r = 0; r < 4; ++r) {
          const float* xa = xb_ + (((size_t)((lk << 2) + r)) << 10) + (hh << 4);
          asm volatile("global_load_dword %0, %1, off"
                       : "=v"(xp[hh][r]) : "v"(xa) : "memory");
        }
    }

    // ---- per-slice poll: wave w waits for its 8 producer blocks (1 line) ----
    {
      const unsigned int need = (unsigned int)(t + 1);
      while (true) {
        unsigned int v = __hip_atomic_load(spoll, __ATOMIC_RELAXED, __HIP_MEMORY_SCOPE_AGENT);
        if (__all((int)(v >= need))) break;
        __builtin_amdgcn_s_sleep(1);
      }
    }
    __builtin_amdgcn_sched_barrier(0);
    // FIFO is empty here (poll's implicit vmcnt(0) drained X + prior stores).

    // ---- issue all 8 A-fragment loads (LLC-direct), then staged MFMA ----
    bf16x8 a[8];
    const char* abase = hin + (dm << 15);
#pragma unroll
    for (int j = 0; j < 8; ++j) {
      const char* ap = abase + (((w << 3) + j) << 10) + (l << 4);
      asm volatile("global_load_dwordx4 %0, %1, off sc0 sc1"
                   : "=v"(a[j]) : "v"(ap) : "memory");
    }
    f32x4 acc[8];
#pragma unroll
    for (int nt = 0; nt < 8; ++nt)
#pragma unroll
      for (int r = 0; r < 4; ++r) acc[nt][r] = 0.f;

#define STAGE(J, CNT)                                                        \
    asm volatile("s_waitcnt vmcnt(" #CNT ")" ::: "memory");                  \
    __builtin_amdgcn_sched_barrier(0);                                       \
    acc[0] = __builtin_amdgcn_mfma_f32_16x16x32_bf16(a[J], Breg[0][J], acc[0], 0, 0, 0); \
    acc[1] = __builtin_amdgcn_mfma_f32_16x16x32_bf16(a[J], Breg[1][J], acc[1], 0, 0, 0); \
    acc[2] = __builtin_amdgcn_mfma_f32_16x16x32_bf16(a[J], Breg[2][J], acc[2], 0, 0, 0); \
    acc[3] = __builtin_amdgcn_mfma_f32_16x16x32_bf16(a[J], Breg[3][J], acc[3], 0, 0, 0); \
    acc[4] = __builtin_amdgcn_mfma_f32_16x16x32_bf16(a[J], Breg[4][J], acc[4], 0, 0, 0); \
    acc[5] = __builtin_amdgcn_mfma_f32_16x16x32_bf16(a[J], Breg[5][J], acc[5], 0, 0, 0); \
    acc[6] = __builtin_amdgcn_mfma_f32_16x16x32_bf16(a[J], Breg[6][J], acc[6], 0, 0, 0); \
    acc[7] = __builtin_amdgcn_mfma_f32_16x16x32_bf16(a[J], Breg[7][J], acc[7], 0, 0, 0);
    STAGE(0, 7) STAGE(1, 6) STAGE(2, 5) STAGE(3, 4)
    STAGE(4, 3) STAGE(5, 2) STAGE(6, 1) STAGE(7, 0)
#undef STAGE

    // ---- write K-partials to LDS ----
#pragma unroll
    for (int nt = 0; nt < 8; ++nt)
      *(f32x4*)(lds + (((w << 3) + nt) << 10) + (l << 4)) = acc[nt];
    __syncthreads();

    // ---- gate-reduce: wave w sums gate w (nt=2w,2w+1) over 4 K-partials ----
#pragma unroll
    for (int hh = 0; hh < 2; ++hh) {
      const int nt = (w << 1) + hh;
      f32x4 s = *(const f32x4*)(lds + (nt << 10) + (l << 4));
#pragma unroll
      for (int kw = 1; kw < 4; ++kw) {
        f32x4 p = *(const f32x4*)(lds + (((kw << 3) + nt) << 10) + (l << 4));
#pragma unroll
        for (int r = 0; r < 4; ++r) s[r] += p[r];
      }
#pragma unroll
      for (int r = 0; r < 4; ++r) {
        float pre = s[r] + xp[hh][r];
        float act = (w == 2) ? tanh_f(pre) : sigm(pre);
        ((float*)(lds + ACT))[((w << 4) + (lk << 2) + r) * 34 + (hh << 4) + ln] = act;
      }
    }
    __syncthreads();

    // ---- pointwise ----
    const float* af = (const float*)(lds + ACT);
    float2 iv = *(const float2*)&af[(0 * 16 + pb) * 34 + o];
    float2 fv = *(const float2*)&af[(1 * 16 + pb) * 34 + o];
    float2 gv = *(const float2*)&af[(2 * 16 + pb) * 34 + o];
    float2 ov = *(const float2*)&af[(3 * 16 + pb) * 34 + o];

    c.x = fv.x * c.x + iv.x * gv.x;
    c.y = fv.y * c.y + iv.y * gv.y;
    float h0v = ov.x * tanh_f(c.x), h1v = ov.y * tanh_f(c.y);

    // ---- publish h_{t+1}: data stores, drain, barrier, ONE sentinel store ----
    if (t < S_LEN - 1) {
      unsigned int pv = (unsigned int)f2bf(h0v) | ((unsigned int)f2bf(h1v) << 16);
      __hip_atomic_store((unsigned int*)(hout + foff), pv, __ATOMIC_RELAXED,
                         __HIP_MEMORY_SCOPE_AGENT);
      asm volatile("s_waitcnt vmcnt(0)" ::: "memory");
      __syncthreads();
      if (tid == 0)
        __hip_atomic_store(smy, (unsigned int)(t + 2), __ATOMIC_RELAXED,
                           __HIP_MEMORY_SCOPE_AGENT);
    }

    // ---- fire-and-forget outputs (drain during next poll) ----
    size_t oo = ((size_t)((t << 5) + bg) << 10) + gh;
    *(float2*)(isw + oo) = iv;
    *(float2*)(fsw + oo) = fv;
    *(float2*)(gsw + oo) = gv;
    *(float2*)(osw + oo) = ov;
    *(float2*)(csw + oo) = c;
    *(float2*)(hseq + (((size_t)(bg << 9) + t) << 10) + gh) = make_float2(h0v, h1v);
    if (t == S_LEN - 1) {
      *(float2*)(hT + ((size_t)bg << 10) + gh) = make_float2(h0v, h1v);
      *(float2*)(cT + ((size_t)bg << 10) + gh) = c;
    }
  }
}

extern "C" void kernel_launch(void* const* d_in, const int* in_sizes, int n_in,
                              void* d_out, int out_size, void* d_ws, size_t ws_size,
                              hipStream_t stream) {
  const float* x = (const float*)d_in[0];
  const float* h0 = (const float*)d_in[1];
  const float* c0 = (const float*)d_in[2];
  const float* Wi[4] = {(const float*)d_in[3], (const float*)d_in[6], (const float*)d_in[9], (const float*)d_in[12]};
  const float* Wh[4] = {(const float*)d_in[4], (const float*)d_in[7], (const float*)d_in[10], (const float*)d_in[13]};
  const float* bias[4] = {(const float*)d_in[5], (const float*)d_in[8], (const float*)d_in[11], (const float*)d_in[14]};

  float* out = (float*)d_out;
  float* R0 = out;               // hidden_seq (B,S,H)
  float* R1 = out + 16777216;    // hT
  float* R2 = R1 + 32768;        // cT
  float* R3 = R2 + 32768;        // fs (S,B,H)
  float* R4 = R3 + 16777216;     // is
  float* R5 = R4 + 16777216;     // os
  float* R6 = R5 + 16777216;     // gs
  float* R7 = R6 + 16777216;     // cs
  float* Xg_[4] = {R4, R3, R6, R5};  // stash region per gate i,f,g,o

  char* ws = (char*)d_ws;
  unsigned short* whb = (unsigned short*)ws;                // 8 MB
  unsigned short* wib = (unsigned short*)(ws + 8388608);    // 4 MB
  char* hbufA = ws + 12582912;                              // 64 KB (2 domains x 32 KB)
  char* hbufB = ws + 12648448;                              // 64 KB
  unsigned int* sent = (unsigned int*)(ws + 12713984);      // 2 x 512B sentinel lines

  unsigned short* xb = (unsigned short*)R0;  // x in bf16, stashed in hidden_seq region

  hipMemsetAsync(sent, 0, 1024, stream);
  k_cast_x<<<2048, 256, 0, stream>>>(x, xb, (BATCH * S_LEN * IDIM) / 8);
  for (int g = 0; g < 4; ++g) {
    k_tcast_w<<<dim3(8, 16), 256, 0, stream>>>(Wi[g], wib + (size_t)g * 1024 * 512, 512);
    k_tcast_w<<<dim3(16, 16), 256, 0, stream>>>(Wh[g], whb + (size_t)g * 1024 * 1024, 1024);
  }
  k_proj<<<4096, 256, 0, stream>>>(xb, wib, bias[0], bias[1], bias[2], bias[3],
                                   Xg_[0], Xg_[1], Xg_[2], Xg_[3]);
  k_rnn<<<NBLK, 256, 0, stream>>>(whb, h0, c0, hbufA, hbufB, sent,
                                  Xg_[0], Xg_[1], Xg_[2], Xg_[3],
                                  R7, R0, R1, R2);
}